// Round 6
// baseline (1138.724 us; speedup 1.0000x reference)
//
// Round 6 = round 4 kernel resubmitted verbatim (rounds 4 and 5 both died on
// UnresponsiveContainer infra errors from the same pod before any compile/run).
// Theory under test: d_out is 400000 float32 (real part of U h U^dag);
// rounds 1/3 aborted from writing 8 floats/node (3.2MB) into a 1.6MB buffer.
// Mode is selected from out_size at launch (8N => complex64 fallback).
#include <hip/hip_runtime.h>

#define PI_F     3.14159265358979323846f
#define TWO_PI_F 6.28318530717958647692f

__device__ __forceinline__ float fast_rcp(float x) { return __builtin_amdgcn_rcpf(x); }

__device__ __forceinline__ float silu_f(float v) {
    return v * fast_rcp(1.0f + __expf(-v));   // v * sigmoid(v)
}

__device__ __forceinline__ float tanh_f(float z) {
    float ez = __expf(2.0f * z);
    return 1.0f - 2.0f * fast_rcp(ez + 1.0f);
}

// MLP 14 -> 64 -> 64 -> 4 with silu on first two layers.
// Weight indices are wave-uniform and contiguous in j => scalar s_load path.
__device__ __forceinline__ void mlp14_64_64_4(
    const float x[14],
    const float* __restrict__ W1, const float* __restrict__ b1,
    const float* __restrict__ W2, const float* __restrict__ b2,
    const float* __restrict__ W3, const float* __restrict__ b3,
    float A[4])
{
    float h1[64];
    #pragma unroll
    for (int j = 0; j < 64; ++j) h1[j] = b1[j];
    #pragma unroll
    for (int k = 0; k < 14; ++k) {
        const float xk = x[k];
        #pragma unroll
        for (int j = 0; j < 64; ++j) h1[j] += xk * W1[k * 64 + j];
    }
    #pragma unroll
    for (int j = 0; j < 64; ++j) h1[j] = silu_f(h1[j]);

    float h2[64];
    #pragma unroll
    for (int j = 0; j < 64; ++j) h2[j] = b2[j];
    #pragma unroll
    for (int k = 0; k < 64; ++k) {
        const float hk = h1[k];
        #pragma unroll
        for (int j = 0; j < 64; ++j) h2[j] += hk * W2[k * 64 + j];
    }
    #pragma unroll
    for (int j = 0; j < 64; ++j) h2[j] = silu_f(h2[j]);

    float a0 = b3[0], a1 = b3[1], a2 = b3[2], a3 = b3[3];
    #pragma unroll
    for (int k = 0; k < 64; ++k) {
        const float hk = h2[k];
        a0 += hk * W3[k * 4 + 0];
        a1 += hk * W3[k * 4 + 1];
        a2 += hk * W3[k * 4 + 2];
        a3 += hk * W3[k * 4 + 3];
    }
    A[0] = a0; A[1] = a1; A[2] = a2; A[3] = a3;
}

__global__ __launch_bounds__(256) void qgnn_zero_kernel(float* __restrict__ p, int n) {
    const int i = blockIdx.x * blockDim.x + threadIdx.x;
    if (i < n) p[i] = 0.0f;
}

template<int STRIDE>
__global__ __launch_bounds__(256) void qgnn_edge_kernel(
    const float* __restrict__ hr,   // (N,2,2) flat
    const float* __restrict__ hi,   // (N,2,2) flat
    const int*   __restrict__ ei,   // (2,E) flat
    const float* __restrict__ npar, // (N,2)
    const float* __restrict__ epar, // (N,1)
    const float* __restrict__ Wa, const float* __restrict__ ba,
    const float* __restrict__ Wr1, const float* __restrict__ br1,
    const float* __restrict__ Wr2, const float* __restrict__ br2,
    const float* __restrict__ Wr3, const float* __restrict__ br3,
    const float* __restrict__ Wi1, const float* __restrict__ bi1,
    const float* __restrict__ Wi2, const float* __restrict__ bi2,
    const float* __restrict__ Wi3, const float* __restrict__ bi3,
    float* __restrict__ aggout,     // agg[n][t] at aggout[STRIDE*n+t], t<3
    int E)
{
    const int e = blockIdx.x * blockDim.x + threadIdx.x;
    if (e >= E) return;

    const int s = ei[e];
    const int r = ei[E + e];

    // ep gather: edge_params[edge_index].reshape(E,2) row-major flatten
    // => ep[e] = (P[ei_flat[2e]], P[ei_flat[2e+1]])
    const float ep0 = epar[ei[2 * e + 0]];
    const float ep1 = epar[ei[2 * e + 1]];

    const float4 hrs = *reinterpret_cast<const float4*>(hr + 4 * (size_t)s);
    const float4 hrr = *reinterpret_cast<const float4*>(hr + 4 * (size_t)r);
    const float2 nps = *reinterpret_cast<const float2*>(npar + 2 * (size_t)s);
    const float2 npr = *reinterpret_cast<const float2*>(npar + 2 * (size_t)r);

    float x[14];
    x[0] = hrs.x; x[1] = hrs.y; x[2] = hrs.z; x[3] = hrs.w;
    x[4] = hrr.x; x[5] = hrr.y; x[6] = hrr.z; x[7] = hrr.w;
    x[8] = nps.x; x[9] = nps.y; x[10] = npr.x; x[11] = npr.y;
    x[12] = ep0;  x[13] = ep1;

    float Ar[4];
    mlp14_64_64_4(x, Wr1, br1, Wr2, br2, Wr3, br3, Ar);

    const float4 his = *reinterpret_cast<const float4*>(hi + 4 * (size_t)s);
    const float4 hir = *reinterpret_cast<const float4*>(hi + 4 * (size_t)r);
    x[0] = his.x; x[1] = his.y; x[2] = his.z; x[3] = his.w;
    x[4] = hir.x; x[5] = hir.y; x[6] = hir.z; x[7] = hir.w;

    float Ai[4];
    mlp14_64_64_4(x, Wi1, bi1, Wi2, bi2, Wi3, bi3, Ai);

    // angles = tanh(concat([A_imag, A_real]) @ Wa + ba); m_ij = angles * pi
    #pragma unroll
    for (int t = 0; t < 3; ++t) {
        float z = ba[t];
        #pragma unroll
        for (int j = 0; j < 4; ++j) z += Ai[j] * Wa[j * 3 + t];
        #pragma unroll
        for (int j = 0; j < 4; ++j) z += Ar[j] * Wa[(4 + j) * 3 + t];
        const float m = tanh_f(z) * PI_F;
        atomicAdd(aggout + (size_t)STRIDE * (size_t)r + t, m);
    }
}

__device__ __forceinline__ float wrap_pi(float v) {
    // jnp: (v + pi) % (2*pi) - pi, with % returning non-negative remainder
    float rm = fmodf(v + PI_F, TWO_PI_F);
    if (rm < 0.0f) rm += TWO_PI_F;
    return rm - PI_F;
}

template<int STRIDE, bool WRITE_COMPLEX>
__global__ __launch_bounds__(256) void qgnn_node_kernel(
    const float* __restrict__ hr,
    const float* __restrict__ hi,
    float* __restrict__ out,   // reads agg from [STRIDE*n .. +2], overwrites own slot
    int N)
{
    const int n = blockIdx.x * blockDim.x + threadIdx.x;
    if (n >= N) return;

    const float a = wrap_pi(out[(size_t)STRIDE * n + 0]);
    const float b = wrap_pi(out[(size_t)STRIDE * n + 1]);
    const float c = wrap_pi(out[(size_t)STRIDE * n + 2]);

    const float cb = __cosf(0.5f * b);
    const float sb = __sinf(0.5f * b);
    const float hpc = 0.5f * (a + c);
    const float hmc = 0.5f * (a - c);
    const float cpc = __cosf(hpc), spc = __sinf(hpc);
    const float cmc = __cosf(hmc), smc = __sinf(hmc);

    // U = [[e^{-i(a+c)/2} cb, -e^{-i(a-c)/2} sb],
    //      [e^{+i(a-c)/2} sb,  e^{+i(a+c)/2} cb]]
    float Ur[2][2], Ui[2][2];
    Ur[0][0] =  cpc * cb;  Ui[0][0] = -spc * cb;
    Ur[0][1] = -cmc * sb;  Ui[0][1] =  smc * sb;
    Ur[1][0] =  cmc * sb;  Ui[1][0] =  smc * sb;
    Ur[1][1] =  cpc * cb;  Ui[1][1] =  spc * cb;

    const float4 h4r = *reinterpret_cast<const float4*>(hr + 4 * (size_t)n);
    const float4 h4i = *reinterpret_cast<const float4*>(hi + 4 * (size_t)n);
    float Hr[2][2] = {{h4r.x, h4r.y}, {h4r.z, h4r.w}};
    float Hi[2][2] = {{h4i.x, h4i.y}, {h4i.z, h4i.w}};

    // T = H @ U^dagger : T[p][j] = sum_t H[p][t] * conj(U[j][t])
    float Tr[2][2], Ti[2][2];
    #pragma unroll
    for (int p = 0; p < 2; ++p) {
        #pragma unroll
        for (int j = 0; j < 2; ++j) {
            float tr = 0.0f, ti = 0.0f;
            #pragma unroll
            for (int t = 0; t < 2; ++t) {
                tr += Hr[p][t] * Ur[j][t] + Hi[p][t] * Ui[j][t];
                ti += Hi[p][t] * Ur[j][t] - Hr[p][t] * Ui[j][t];
            }
            Tr[p][j] = tr; Ti[p][j] = ti;
        }
    }

    // out = U @ T
    float orr[2][2], oii[2][2];
    #pragma unroll
    for (int i = 0; i < 2; ++i) {
        #pragma unroll
        for (int j = 0; j < 2; ++j) {
            float xr = 0.0f, xi = 0.0f;
            #pragma unroll
            for (int p = 0; p < 2; ++p) {
                xr += Ur[i][p] * Tr[p][j] - Ui[i][p] * Ti[p][j];
                xi += Ur[i][p] * Ti[p][j] + Ui[i][p] * Tr[p][j];
            }
            orr[i][j] = xr; oii[i][j] = xi;
        }
    }

    if (WRITE_COMPLEX) {
        float4* outv = reinterpret_cast<float4*>(out + (size_t)STRIDE * n);
        outv[0] = make_float4(orr[0][0], oii[0][0], orr[0][1], oii[0][1]);
        outv[1] = make_float4(orr[1][0], oii[1][0], orr[1][1], oii[1][1]);
    } else {
        // real part only, row-major (n,2,2)
        *reinterpret_cast<float4*>(out + (size_t)STRIDE * n) =
            make_float4(orr[0][0], orr[0][1], orr[1][0], orr[1][1]);
    }
}

extern "C" void kernel_launch(void* const* d_in, const int* in_sizes, int n_in,
                              void* d_out, int out_size, void* d_ws, size_t ws_size,
                              hipStream_t stream) {
    const float* hr   = (const float*)d_in[0];
    const float* hi   = (const float*)d_in[1];
    const int*   ei   = (const int*)  d_in[2];
    const float* npar = (const float*)d_in[3];
    const float* epar = (const float*)d_in[4];
    const float* Wa  = (const float*)d_in[5];
    const float* ba  = (const float*)d_in[6];
    const float* Wr1 = (const float*)d_in[7];
    const float* br1 = (const float*)d_in[8];
    const float* Wr2 = (const float*)d_in[9];
    const float* br2 = (const float*)d_in[10];
    const float* Wr3 = (const float*)d_in[11];
    const float* br3 = (const float*)d_in[12];
    const float* Wi1 = (const float*)d_in[13];
    const float* bi1 = (const float*)d_in[14];
    const float* Wi2 = (const float*)d_in[15];
    const float* bi2 = (const float*)d_in[16];
    const float* Wi3 = (const float*)d_in[17];
    const float* bi3 = (const float*)d_in[18];

    const int N = in_sizes[0] / 4;   // h_i_real is (N,2,2)
    const int E = in_sizes[2] / 2;   // edge_index is (2,E)

    float* out = (float*)d_out;
    const bool cplx = (out_size >= 8 * N);   // 8 floats/node (complex64) vs 4 (real)

    // Zero the output; first 3 floats of each node slot double as the
    // segment-sum accumulator. Writes stay strictly within out_size floats.
    const int total = cplx ? 8 * N : 4 * N;
    qgnn_zero_kernel<<<(total + 255) / 256, 256, 0, stream>>>(out, total);

    if (cplx) {
        qgnn_edge_kernel<8><<<(E + 255) / 256, 256, 0, stream>>>(
            hr, hi, ei, npar, epar, Wa, ba,
            Wr1, br1, Wr2, br2, Wr3, br3,
            Wi1, bi1, Wi2, bi2, Wi3, bi3, out, E);
        qgnn_node_kernel<8, true><<<(N + 255) / 256, 256, 0, stream>>>(hr, hi, out, N);
    } else {
        qgnn_edge_kernel<4><<<(E + 255) / 256, 256, 0, stream>>>(
            hr, hi, ei, npar, epar, Wa, ba,
            Wr1, br1, Wr2, br2, Wr3, br3,
            Wi1, bi1, Wi2, bi2, Wi3, bi3, out, E);
        qgnn_node_kernel<4, false><<<(N + 255) / 256, 256, 0, stream>>>(hr, hi, out, N);
    }
}